// Round 1
// baseline (107.411 us; speedup 1.0000x reference)
//
#include <hip/hip_runtime.h>

typedef float  f32x4 __attribute__((ext_vector_type(4)));
typedef float  f4v   __attribute__((ext_vector_type(4)));
typedef short  s16x8 __attribute__((ext_vector_type(8)));
typedef unsigned short u16x4 __attribute__((ext_vector_type(4)));
typedef unsigned short u16;

#define DEVI static __device__ __forceinline__

DEVI u16 f2bf(float f) {
  unsigned int u = __builtin_bit_cast(unsigned int, f);
  u += 0x7FFFu + ((u >> 16) & 1u);   // RNE; inputs are normal floats
  return (u16)(u >> 16);
}

// ---------------------------------------------------------------------------
// sizes
constexpr int B  = 8;
constexpr int L  = 2048;
constexpr int D  = 64;     // d_k == d_v
constexpr int DM = 1024;   // d_model
constexpr int QB = 64;     // q rows per block
constexpr int KVB = 64;    // kv rows per tile
constexpr int NT = L / KVB;

// ---------------------------------------------------------------------------
// prep: kbf = bf16(k * 0.125) [b][l][d] ; wbf = bf16(fc_w) [m][v] ;
//       vtbf = bf16(v^T) [b][dv][l]
__global__ void prep_kernel(const float* __restrict__ k, const float* __restrict__ v,
                            const float* __restrict__ w,
                            u16* __restrict__ kbf, u16* __restrict__ vtbf,
                            u16* __restrict__ wbf) {
  __shared__ float tile[64 * 65];
  const int bid = blockIdx.x, tid = threadIdx.x;
  if (bid < 1024) {                       // k: 8*2048*64 = 1,048,576 elems
    const int i = bid * 256 + tid;
    f4v f = ((const f4v*)k)[i];
    u16x4 o;
#pragma unroll
    for (int j = 0; j < 4; ++j) o[j] = f2bf(f[j] * 0.125f);
    ((u16x4*)kbf)[i] = o;
  } else if (bid < 1024 + 64) {           // w: 65,536 elems
    const int i = (bid - 1024) * 256 + tid;
    f4v f = ((const f4v*)w)[i];
    u16x4 o;
#pragma unroll
    for (int j = 0; j < 4; ++j) o[j] = f2bf(f[j]);
    ((u16x4*)wbf)[i] = o;
  } else {                                // v transpose: 8*32 = 256 tiles of 64x64
    const int t2 = bid - 1088;
    const int b = t2 >> 5, tt = t2 & 31;
    const float* vp = v + ((size_t)b * L + tt * 64) * D;
    for (int i = tid; i < 4096; i += 256) {
      const int r = i >> 6, c = i & 63;
      tile[c * 65 + r] = vp[i];           // coalesced read, conflict-free write
    }
    __syncthreads();
    u16* op = vtbf + (size_t)b * D * L + tt * 64;
    for (int i = tid; i < 4096; i += 256) {
      const int dv = i >> 6, kv = i & 63;
      op[(size_t)dv * L + kv] = f2bf(tile[dv * 65 + kv]);
    }
  }
}

// ---------------------------------------------------------------------------
// flash attention: O[b][l][dv] f32
__global__ __launch_bounds__(256) void attn_kernel(const float* __restrict__ q,
                                                   const u16* __restrict__ kbf,
                                                   const u16* __restrict__ vtbf,
                                                   float* __restrict__ Og) {
  const int qt = blockIdx.x, b = blockIdx.y;
  const int tid = threadIdx.x;
  const int wave = tid >> 6, lane = tid & 63;
  const int lg = lane >> 4, ln = lane & 15;

  __shared__ __align__(16) u16 Kt[2][KVB * D];   // [kv][d] row-major, 16B-chunk XOR-swizzled
  __shared__ __align__(16) u16 Vt[2][D * KVB];   // [dv][kv] row-major, swizzled
  __shared__ __align__(16) u16 Pl[4][16 * 72];   // per-wave P tile, padded rows

  // Q A-fragments: A[m=q][k=d], m=lane%16, k=8*(lane/16)+i (contiguous)
  s16x8 aq[2];
  {
    const float* qp = q + ((size_t)b * L + (size_t)qt * QB + wave * 16 + ln) * D + lg * 8;
#pragma unroll
    for (int kk = 0; kk < 2; ++kk) {
      f4v f0 = *(const f4v*)(qp + kk * 32);
      f4v f1 = *(const f4v*)(qp + kk * 32 + 4);
      s16x8 a;
#pragma unroll
      for (int j = 0; j < 4; ++j) { a[j] = (short)f2bf(f0[j]); a[4 + j] = (short)f2bf(f1[j]); }
      aq[kk] = a;
    }
  }

  const f32x4 zf = {0.f, 0.f, 0.f, 0.f};
  f32x4 acc[4];
#pragma unroll
  for (int i = 0; i < 4; ++i) acc[i] = zf;
  float mrow[4], lrow[4];
#pragma unroll
  for (int r = 0; r < 4; ++r) { mrow[r] = -1e30f; lrow[r] = 0.f; }

  const u16* kb = kbf + (size_t)b * L * D;
  const u16* vb = vtbf + (size_t)b * D * L;

  auto stage = [&](int buf, int t) {
    const int kv0 = t * KVB;
#pragma unroll
    for (int i = 0; i < 2; ++i) {
      const int c = tid + i * 256;          // chunk id: 64 rows x 8 chunks of 16B
      const int row = c >> 3, jl = c & 7;
      const int js = jl ^ (row & 7);        // inverse swizzle on the SOURCE
      const u16* srcK = kb + (size_t)(kv0 + row) * D + js * 8;
      __builtin_amdgcn_global_load_lds(
          (const __attribute__((address_space(1))) unsigned int*)srcK,
          (__attribute__((address_space(3))) unsigned int*)&Kt[buf][c * 8], 16, 0, 0);
      const u16* srcV = vb + (size_t)row * L + kv0 + js * 8;
      __builtin_amdgcn_global_load_lds(
          (const __attribute__((address_space(1))) unsigned int*)srcV,
          (__attribute__((address_space(3))) unsigned int*)&Vt[buf][c * 8], 16, 0, 0);
    }
  };

  stage(0, 0);

  for (int t = 0; t < NT; ++t) {
    __syncthreads();                        // stage(t) landed; tile t-1 fully consumed
    if (t + 1 < NT) stage((t + 1) & 1, t + 1);
    const int buf = t & 1;

    // S = Q K^T (temperature folded into kbf)
    f32x4 s[4];
#pragma unroll
    for (int i = 0; i < 4; ++i) s[i] = zf;
#pragma unroll
    for (int kk = 0; kk < 2; ++kk) {
#pragma unroll
      for (int fn = 0; fn < 4; ++fn) {
        const int kv = fn * 16 + ln;
        const int j = (kk * 4 + lg) ^ (kv & 7);
        s16x8 bk = *(const s16x8*)&Kt[buf][kv * 64 + j * 8];
        s[fn] = __builtin_amdgcn_mfma_f32_16x16x32_bf16(aq[kk], bk, s[fn], 0, 0, 0);
      }
    }

    // online softmax; D-layout row = lg*4+r, col = fn*16+ln
#pragma unroll
    for (int r = 0; r < 4; ++r) {
      float mx = fmaxf(fmaxf(s[0][r], s[1][r]), fmaxf(s[2][r], s[3][r]));
#pragma unroll
      for (int off = 1; off < 16; off <<= 1) mx = fmaxf(mx, __shfl_xor(mx, off, 64));
      const float mnew = fmaxf(mrow[r], mx);
      const float corr = __expf(mrow[r] - mnew);
      mrow[r] = mnew;
      float ps = 0.f;
#pragma unroll
      for (int fn = 0; fn < 4; ++fn) {
        const float p = __expf(s[fn][r] - mnew);
        ps += p;
        Pl[wave][(lg * 4 + r) * 72 + fn * 16 + ln] = f2bf(p);
      }
#pragma unroll
      for (int off = 1; off < 16; off <<= 1) ps += __shfl_xor(ps, off, 64);
      lrow[r] = lrow[r] * corr + ps;
#pragma unroll
      for (int fn = 0; fn < 4; ++fn) acc[fn][r] *= corr;
    }

    asm volatile("" ::: "memory");          // keep P writes before P reads (same wave)

    // O += P V ; A[m=q][k=kv] from Pl, B[k=kv][n=dv] from Vt
#pragma unroll
    for (int kk = 0; kk < 2; ++kk) {
      s16x8 ap = *(const s16x8*)&Pl[wave][ln * 72 + kk * 32 + lg * 8];
#pragma unroll
      for (int fn = 0; fn < 4; ++fn) {
        const int dv = fn * 16 + ln;
        const int j = (kk * 4 + lg) ^ (dv & 7);
        s16x8 bv = *(const s16x8*)&Vt[buf][dv * 64 + j * 8];
        acc[fn] = __builtin_amdgcn_mfma_f32_16x16x32_bf16(ap, bv, acc[fn], 0, 0, 0);
      }
    }
  }

  float inv[4];
#pragma unroll
  for (int r = 0; r < 4; ++r) inv[r] = 1.f / lrow[r];
  float* Op = Og + ((size_t)b * L + (size_t)qt * QB + wave * 16) * D;
#pragma unroll
  for (int fn = 0; fn < 4; ++fn)
#pragma unroll
    for (int r = 0; r < 4; ++r)
      Op[(lg * 4 + r) * D + fn * 16 + ln] = acc[fn][r] * inv[r];
}

// ---------------------------------------------------------------------------
// FC (MFMA) + bias + residual + LayerNorm
__global__ __launch_bounds__(256) void fc_ln_kernel(const float* __restrict__ Og,
                                                    const u16* __restrict__ wbf,
                                                    const float* __restrict__ bias,
                                                    const float* __restrict__ resid,
                                                    const float* __restrict__ gamma,
                                                    const float* __restrict__ beta,
                                                    float* __restrict__ out) {
  const int row0 = blockIdx.x * 16;        // flattened b*L + l
  const int tid = threadIdx.x;
  const int wave = tid >> 6, lane = tid & 63;
  const int lg = lane >> 4, ln = lane & 15;

  s16x8 ao[2];
  {
    const float* op = Og + (size_t)(row0 + ln) * D + lg * 8;
#pragma unroll
    for (int kk = 0; kk < 2; ++kk) {
      f4v f0 = *(const f4v*)(op + kk * 32);
      f4v f1 = *(const f4v*)(op + kk * 32 + 4);
      s16x8 a;
#pragma unroll
      for (int j = 0; j < 4; ++j) { a[j] = (short)f2bf(f0[j]); a[4 + j] = (short)f2bf(f1[j]); }
      ao[kk] = a;
    }
  }

  const f32x4 zf = {0.f, 0.f, 0.f, 0.f};
  f32x4 acc[16];
#pragma unroll
  for (int i = 0; i < 16; ++i) acc[i] = zf;

#pragma unroll
  for (int fn = 0; fn < 16; ++fn) {
    const int m = wave * 256 + fn * 16 + ln;
#pragma unroll
    for (int kk = 0; kk < 2; ++kk) {
      s16x8 bw = *(const s16x8*)&wbf[(size_t)m * D + kk * 32 + lg * 8];
      acc[fn] = __builtin_amdgcn_mfma_f32_16x16x32_bf16(ao[kk], bw, acc[fn], 0, 0, 0);
    }
  }

  float sum[4] = {0.f, 0.f, 0.f, 0.f}, ssq[4] = {0.f, 0.f, 0.f, 0.f};
#pragma unroll
  for (int fn = 0; fn < 16; ++fn) {
    const int m = wave * 256 + fn * 16 + ln;
    const float bm = bias[m];
#pragma unroll
    for (int r = 0; r < 4; ++r) {
      const int rw = lg * 4 + r;
      float x = acc[fn][r] + bm + resid[(size_t)(row0 + rw) * DM + m];
      acc[fn][r] = x;
      sum[r] += x;
      ssq[r] += x * x;
    }
  }
#pragma unroll
  for (int r = 0; r < 4; ++r) {
#pragma unroll
    for (int off = 1; off < 16; off <<= 1) {
      sum[r] += __shfl_xor(sum[r], off, 64);
      ssq[r] += __shfl_xor(ssq[r], off, 64);
    }
  }
  __shared__ float part[4][16][2];
  if (ln == 0) {
#pragma unroll
    for (int r = 0; r < 4; ++r) {
      part[wave][lg * 4 + r][0] = sum[r];
      part[wave][lg * 4 + r][1] = ssq[r];
    }
  }
  __syncthreads();
  float mean[4], rstd[4];
#pragma unroll
  for (int r = 0; r < 4; ++r) {
    const int rw = lg * 4 + r;
    float sm = 0.f, q2 = 0.f;
#pragma unroll
    for (int w2 = 0; w2 < 4; ++w2) { sm += part[w2][rw][0]; q2 += part[w2][rw][1]; }
    const float mu = sm * (1.0f / 1024.0f);
    const float var = q2 * (1.0f / 1024.0f) - mu * mu;
    mean[r] = mu;
    rstd[r] = rsqrtf(var + 1e-5f);
  }
#pragma unroll
  for (int fn = 0; fn < 16; ++fn) {
    const int m = wave * 256 + fn * 16 + ln;
    const float gm = gamma[m], bt = beta[m];
#pragma unroll
    for (int r = 0; r < 4; ++r) {
      const int rw = lg * 4 + r;
      out[(size_t)(row0 + rw) * DM + m] = (acc[fn][r] - mean[r]) * rstd[r] * gm + bt;
    }
  }
}

// ---------------------------------------------------------------------------
extern "C" void kernel_launch(void* const* d_in, const int* in_sizes, int n_in,
                              void* d_out, int out_size, void* d_ws, size_t ws_size,
                              hipStream_t stream) {
  const float* q     = (const float*)d_in[0];
  const float* k     = (const float*)d_in[1];
  const float* v     = (const float*)d_in[2];
  const float* resid = (const float*)d_in[3];
  const float* fc_w  = (const float*)d_in[4];
  const float* fc_b  = (const float*)d_in[5];
  const float* gamma = (const float*)d_in[6];
  const float* beta  = (const float*)d_in[7];
  float* out = (float*)d_out;

  char* ws = (char*)d_ws;
  u16*   kbf  = (u16*)(ws);                               // 2 MB
  u16*   vtbf = (u16*)(ws + (2u << 20));                  // 2 MB
  u16*   wbf  = (u16*)(ws + (4u << 20));                  // 128 KB
  float* Og   = (float*)(ws + (4u << 20) + (128u << 10)); // 4 MB

  prep_kernel<<<1344, 256, 0, stream>>>(k, v, fc_w, kbf, vtbf, wbf);
  attn_kernel<<<dim3(L / QB, B), 256, 0, stream>>>(q, kbf, vtbf, Og);
  fc_ln_kernel<<<(B * L) / 16, 256, 0, stream>>>(Og, wbf, fc_b, resid, gamma, beta, out);
}

// Round 2
// 106.537 us; speedup vs baseline: 1.0082x; 1.0082x over previous
//
#include <hip/hip_runtime.h>

typedef float  f32x4 __attribute__((ext_vector_type(4)));
typedef float  f4v   __attribute__((ext_vector_type(4)));
typedef short  s16x8 __attribute__((ext_vector_type(8)));
typedef unsigned short u16x4 __attribute__((ext_vector_type(4)));
typedef unsigned short u16;

#define DEVI static __device__ __forceinline__

DEVI u16 f2bf(float f) {
  unsigned int u = __builtin_bit_cast(unsigned int, f);
  u += 0x7FFFu + ((u >> 16) & 1u);   // RNE; inputs are normal floats
  return (u16)(u >> 16);
}

// ---------------------------------------------------------------------------
// sizes
constexpr int B  = 8;
constexpr int L  = 2048;
constexpr int D  = 64;     // d_k == d_v
constexpr int DM = 1024;   // d_model
constexpr int QB = 64;     // q rows per block
constexpr int KVB = 64;    // kv rows per tile
constexpr int NT = L / KVB;

// ---------------------------------------------------------------------------
// prep: kbf = bf16(k * 0.125) [b][l][d] ; wbf = bf16(fc_w) [m][v] ;
//       vtbf = bf16(v^T) [b][dv][l]
__global__ void prep_kernel(const float* __restrict__ k, const float* __restrict__ v,
                            const float* __restrict__ w,
                            u16* __restrict__ kbf, u16* __restrict__ vtbf,
                            u16* __restrict__ wbf) {
  __shared__ float tile[64 * 65];
  const int bid = blockIdx.x, tid = threadIdx.x;
  if (bid < 1024) {                       // k: 8*2048*64 = 1,048,576 elems
    const int i = bid * 256 + tid;
    f4v f = ((const f4v*)k)[i];
    u16x4 o;
#pragma unroll
    for (int j = 0; j < 4; ++j) o[j] = f2bf(f[j] * 0.125f);
    ((u16x4*)kbf)[i] = o;
  } else if (bid < 1024 + 64) {           // w: 65,536 elems
    const int i = (bid - 1024) * 256 + tid;
    f4v f = ((const f4v*)w)[i];
    u16x4 o;
#pragma unroll
    for (int j = 0; j < 4; ++j) o[j] = f2bf(f[j]);
    ((u16x4*)wbf)[i] = o;
  } else {                                // v transpose: 8*32 = 256 tiles of 64x64
    const int t2 = bid - 1088;
    const int b = t2 >> 5, tt = t2 & 31;
    const float* vp = v + ((size_t)b * L + tt * 64) * D;
    for (int i = tid; i < 4096; i += 256) {
      const int r = i >> 6, c = i & 63;
      tile[c * 65 + r] = vp[i];           // coalesced read, conflict-free write
    }
    __syncthreads();
    u16* op = vtbf + (size_t)b * D * L + tt * 64;
    for (int i = tid; i < 4096; i += 256) {
      const int dv = i >> 6, kv = i & 63;
      op[(size_t)dv * L + kv] = f2bf(tile[dv * 65 + kv]);
    }
  }
}

// ---------------------------------------------------------------------------
// flash attention: O[b][l][dv] f32
__global__ __launch_bounds__(256) void attn_kernel(const float* __restrict__ q,
                                                   const u16* __restrict__ kbf,
                                                   const u16* __restrict__ vtbf,
                                                   float* __restrict__ Og) {
  const int qt = blockIdx.x, b = blockIdx.y;
  const int tid = threadIdx.x;
  const int wave = tid >> 6, lane = tid & 63;
  const int lg = lane >> 4, ln = lane & 15;

  __shared__ __align__(16) u16 Kt[2][KVB * D];   // [kv][d] row-major, 16B-chunk XOR-swizzled
  __shared__ __align__(16) u16 Vt[2][D * KVB];   // [dv][kv] row-major, swizzled
  __shared__ __align__(16) u16 Pl[4][16 * 72];   // per-wave P tile, padded rows

  // Q A-fragments: A[m=q][k=d], m=lane%16, k=8*(lane/16)+i (contiguous)
  s16x8 aq[2];
  {
    const float* qp = q + ((size_t)b * L + (size_t)qt * QB + wave * 16 + ln) * D + lg * 8;
#pragma unroll
    for (int kk = 0; kk < 2; ++kk) {
      f4v f0 = *(const f4v*)(qp + kk * 32);
      f4v f1 = *(const f4v*)(qp + kk * 32 + 4);
      s16x8 a;
#pragma unroll
      for (int j = 0; j < 4; ++j) { a[j] = (short)f2bf(f0[j]); a[4 + j] = (short)f2bf(f1[j]); }
      aq[kk] = a;
    }
  }

  const f32x4 zf = {0.f, 0.f, 0.f, 0.f};
  f32x4 acc[4];
#pragma unroll
  for (int i = 0; i < 4; ++i) acc[i] = zf;
  float mrow[4], lrow[4];
#pragma unroll
  for (int r = 0; r < 4; ++r) { mrow[r] = -1e30f; lrow[r] = 0.f; }

  const u16* kb = kbf + (size_t)b * L * D;
  const u16* vb = vtbf + (size_t)b * D * L;

  auto stage = [&](int buf, int t) {
    const int kv0 = t * KVB;
#pragma unroll
    for (int i = 0; i < 2; ++i) {
      const int c = tid + i * 256;          // chunk id: 64 rows x 8 chunks of 16B
      const int row = c >> 3, jl = c & 7;
      const int js = jl ^ (row & 7);        // inverse swizzle on the SOURCE
      const u16* srcK = kb + (size_t)(kv0 + row) * D + js * 8;
      __builtin_amdgcn_global_load_lds(
          (const __attribute__((address_space(1))) unsigned int*)srcK,
          (__attribute__((address_space(3))) unsigned int*)&Kt[buf][c * 8], 16, 0, 0);
      const u16* srcV = vb + (size_t)row * L + kv0 + js * 8;
      __builtin_amdgcn_global_load_lds(
          (const __attribute__((address_space(1))) unsigned int*)srcV,
          (__attribute__((address_space(3))) unsigned int*)&Vt[buf][c * 8], 16, 0, 0);
    }
  };

  stage(0, 0);

  for (int t = 0; t < NT; ++t) {
    __syncthreads();                        // stage(t) landed; tile t-1 fully consumed
    if (t + 1 < NT) stage((t + 1) & 1, t + 1);
    const int buf = t & 1;

    // S = Q K^T (temperature folded into kbf)
    f32x4 s[4];
#pragma unroll
    for (int i = 0; i < 4; ++i) s[i] = zf;
#pragma unroll
    for (int kk = 0; kk < 2; ++kk) {
#pragma unroll
      for (int fn = 0; fn < 4; ++fn) {
        const int kv = fn * 16 + ln;
        const int j = (kk * 4 + lg) ^ (kv & 7);
        s16x8 bk = *(const s16x8*)&Kt[buf][kv * 64 + j * 8];
        s[fn] = __builtin_amdgcn_mfma_f32_16x16x32_bf16(aq[kk], bk, s[fn], 0, 0, 0);
      }
    }

    // online softmax; D-layout row = lg*4+r, col = fn*16+ln
#pragma unroll
    for (int r = 0; r < 4; ++r) {
      float mx = fmaxf(fmaxf(s[0][r], s[1][r]), fmaxf(s[2][r], s[3][r]));
#pragma unroll
      for (int off = 1; off < 16; off <<= 1) mx = fmaxf(mx, __shfl_xor(mx, off, 64));
      const float mnew = fmaxf(mrow[r], mx);
      const float corr = __expf(mrow[r] - mnew);
      mrow[r] = mnew;
      float ps = 0.f;
#pragma unroll
      for (int fn = 0; fn < 4; ++fn) {
        const float p = __expf(s[fn][r] - mnew);
        ps += p;
        Pl[wave][(lg * 4 + r) * 72 + fn * 16 + ln] = f2bf(p);
      }
#pragma unroll
      for (int off = 1; off < 16; off <<= 1) ps += __shfl_xor(ps, off, 64);
      lrow[r] = lrow[r] * corr + ps;
#pragma unroll
      for (int fn = 0; fn < 4; ++fn) acc[fn][r] *= corr;
    }

    asm volatile("" ::: "memory");          // keep P writes before P reads (same wave)

    // O += P V ; A[m=q][k=kv] from Pl, B[k=kv][n=dv] from Vt
#pragma unroll
    for (int kk = 0; kk < 2; ++kk) {
      s16x8 ap = *(const s16x8*)&Pl[wave][ln * 72 + kk * 32 + lg * 8];
#pragma unroll
      for (int fn = 0; fn < 4; ++fn) {
        const int dv = fn * 16 + ln;
        const int j = (kk * 4 + lg) ^ (dv & 7);
        s16x8 bv = *(const s16x8*)&Vt[buf][dv * 64 + j * 8];
        acc[fn] = __builtin_amdgcn_mfma_f32_16x16x32_bf16(ap, bv, acc[fn], 0, 0, 0);
      }
    }
  }

  float inv[4];
#pragma unroll
  for (int r = 0; r < 4; ++r) inv[r] = 1.f / lrow[r];
  float* Op = Og + ((size_t)b * L + (size_t)qt * QB + wave * 16) * D;
#pragma unroll
  for (int fn = 0; fn < 4; ++fn)
#pragma unroll
    for (int r = 0; r < 4; ++r)
      Op[(lg * 4 + r) * D + fn * 16 + ln] = acc[fn][r] * inv[r];
}

// ---------------------------------------------------------------------------
// FC (MFMA, swapped operands: D[m][row]) + bias + residual + LayerNorm
// Each lane holds 4 CONSECUTIVE m for ONE row -> float4 resid/out traffic.
__global__ __launch_bounds__(256) void fc_ln_kernel(const float* __restrict__ Og,
                                                    const u16* __restrict__ wbf,
                                                    const float* __restrict__ bias,
                                                    const float* __restrict__ resid,
                                                    const float* __restrict__ gamma,
                                                    const float* __restrict__ beta,
                                                    float* __restrict__ out) {
  const int row0 = blockIdx.x * 16;        // flattened b*L + l
  const int tid = threadIdx.x;
  const int wave = tid >> 6, lane = tid & 63;
  const int lg = lane >> 4, ln = lane & 15;
  const int row = row0 + ln;               // this lane's output row

  // B-fragment (O rows): B[k=v][n=row], n=ln, k=kk*32+lg*8+j
  s16x8 bo[2];
  {
    const float* op = Og + (size_t)row * D + lg * 8;
#pragma unroll
    for (int kk = 0; kk < 2; ++kk) {
      f4v f0 = *(const f4v*)(op + kk * 32);
      f4v f1 = *(const f4v*)(op + kk * 32 + 4);
      s16x8 a;
#pragma unroll
      for (int j = 0; j < 4; ++j) { a[j] = (short)f2bf(f0[j]); a[4 + j] = (short)f2bf(f1[j]); }
      bo[kk] = a;
    }
  }

  const f32x4 zf = {0.f, 0.f, 0.f, 0.f};
  f32x4 acc[16];
#pragma unroll
  for (int i = 0; i < 16; ++i) acc[i] = zf;

  // FC:   acc[fn][r] = x for m = wave*256 + fn*16 + lg*4 + r, at row `row`
  // A-fragment (W rows): A[m][k], m = mtile + ln, k = kk*32 + lg*8 + j
  float sum = 0.f, ssq = 0.f;
#pragma unroll
  for (int fn = 0; fn < 16; ++fn) {
    const int mtile = wave * 256 + fn * 16;
    const u16* wp = &wbf[(size_t)(mtile + ln) * D + lg * 8];
    s16x8 aw0 = *(const s16x8*)(wp);
    s16x8 aw1 = *(const s16x8*)(wp + 32);
    acc[fn] = __builtin_amdgcn_mfma_f32_16x16x32_bf16(aw0, bo[0], acc[fn], 0, 0, 0);
    acc[fn] = __builtin_amdgcn_mfma_f32_16x16x32_bf16(aw1, bo[1], acc[fn], 0, 0, 0);
    const int m4 = mtile + lg * 4;
    const f4v bs  = *(const f4v*)&bias[m4];
    const f4v rsd = *(const f4v*)&resid[(size_t)row * DM + m4];
#pragma unroll
    for (int r = 0; r < 4; ++r) {
      const float x = acc[fn][r] + bs[r] + rsd[r];
      acc[fn][r] = x;
      sum += x;
      ssq += x * x;
    }
  }

  // reduce over lg (lanes ln, ln+16, ln+32, ln+48) -> wave-partial for row
  sum += __shfl_xor(sum, 16, 64); ssq += __shfl_xor(ssq, 16, 64);
  sum += __shfl_xor(sum, 32, 64); ssq += __shfl_xor(ssq, 32, 64);

  __shared__ float part[4][16][2];
  if (lg == 0) { part[wave][ln][0] = sum; part[wave][ln][1] = ssq; }
  __syncthreads();
  float sm = 0.f, q2 = 0.f;
#pragma unroll
  for (int w2 = 0; w2 < 4; ++w2) { sm += part[w2][ln][0]; q2 += part[w2][ln][1]; }
  const float mu   = sm * (1.0f / 1024.0f);
  const float var  = q2 * (1.0f / 1024.0f) - mu * mu;
  const float rstd = rsqrtf(var + 1e-5f);

#pragma unroll
  for (int fn = 0; fn < 16; ++fn) {
    const int m4 = wave * 256 + fn * 16 + lg * 4;
    const f4v gm = *(const f4v*)&gamma[m4];
    const f4v bt = *(const f4v*)&beta[m4];
    f4v o;
#pragma unroll
    for (int r = 0; r < 4; ++r) o[r] = (acc[fn][r] - mu) * rstd * gm[r] + bt[r];
    *(f4v*)&out[(size_t)row * DM + m4] = o;
  }
}

// ---------------------------------------------------------------------------
extern "C" void kernel_launch(void* const* d_in, const int* in_sizes, int n_in,
                              void* d_out, int out_size, void* d_ws, size_t ws_size,
                              hipStream_t stream) {
  const float* q     = (const float*)d_in[0];
  const float* k     = (const float*)d_in[1];
  const float* v     = (const float*)d_in[2];
  const float* resid = (const float*)d_in[3];
  const float* fc_w  = (const float*)d_in[4];
  const float* fc_b  = (const float*)d_in[5];
  const float* gamma = (const float*)d_in[6];
  const float* beta  = (const float*)d_in[7];
  float* out = (float*)d_out;

  char* ws = (char*)d_ws;
  u16*   kbf  = (u16*)(ws);                               // 2 MB
  u16*   vtbf = (u16*)(ws + (2u << 20));                  // 2 MB
  u16*   wbf  = (u16*)(ws + (4u << 20));                  // 128 KB
  float* Og   = (float*)(ws + (4u << 20) + (128u << 10)); // 4 MB

  prep_kernel<<<1344, 256, 0, stream>>>(k, v, fc_w, kbf, vtbf, wbf);
  attn_kernel<<<dim3(L / QB, B), 256, 0, stream>>>(q, kbf, vtbf, Og);
  fc_ln_kernel<<<(B * L) / 16, 256, 0, stream>>>(Og, wbf, fc_b, resid, gamma, beta, out);
}